// Round 3
// baseline (5762.699 us; speedup 1.0000x reference)
//
#include <hip/hip_runtime.h>

#define B_ 16
#define N_ 4096
#define M_ 1024
#define S_ 32
#define IN_ 64
#define C0IN 67
#define NTOT (B_*M_*S_)
#define R2 0.04f
#define CAP 1024

// ---------------- FPS ----------------
// 512 threads (8 waves) per batch. 8 pts/lane in registers. One barrier/iter
// (double-buffered partials); every wave redundantly reduces the 8 partials
// so `cur` is uniform without a second barrier.
__global__ __launch_bounds__(512, 1) void fps_kernel(const float* __restrict__ xyz,
                                                     int* __restrict__ fps_idx,
                                                     float* __restrict__ out_xyz) {
#pragma clang fp contract(off)
    __shared__ float px[N_], py[N_], pz[N_];
    __shared__ float rv[2][8];
    __shared__ int   ri[2][8];
    int b = blockIdx.x, t = threadIdx.x;
    const float* xb = xyz + (size_t)b * N_ * 3;
    for (int i = t; i < N_; i += 512) {
        px[i] = xb[i*3+0]; py[i] = xb[i*3+1]; pz[i] = xb[i*3+2];
    }
    __syncthreads();
    float lx[8], ly[8], lz[8], dl[8];
#pragma unroll
    for (int j = 0; j < 8; j++) {
        int i = (j << 9) + t;
        lx[j] = px[i]; ly[j] = py[i]; lz[j] = pz[i];
        dl[j] = __builtin_inff();
    }
    int cur = 0;
    int wv = t >> 6;
    for (int k = 0; k < M_; k++) {
        float cx = px[cur], cy = py[cur], cz = pz[cur];
        if (t == 0) {
            fps_idx[b*M_ + k] = cur;
            out_xyz[(b*M_ + k)*3 + 0] = cx;
            out_xyz[(b*M_ + k)*3 + 1] = cy;
            out_xyz[(b*M_ + k)*3 + 2] = cz;
        }
        float bv = -1.0f; int bi = 0;
#pragma unroll
        for (int j = 0; j < 8; j++) {
            float dx = lx[j] - cx, dy = ly[j] - cy, dz = lz[j] - cz;
            float t0 = dx*dx, t1 = dy*dy, t2 = dz*dz;
            float d = (t0 + t1) + t2;
            float od = dl[j];
            float nd = d < od ? d : od;
            dl[j] = nd;
            if (nd > bv) { bv = nd; bi = (j << 9) + t; }  // strict > keeps first
        }
        for (int off = 32; off >= 1; off >>= 1) {
            float ov = __shfl_xor(bv, off, 64);
            int   oi = __shfl_xor(bi, off, 64);
            if (ov > bv || (ov == bv && oi < bi)) { bv = ov; bi = oi; }
        }
        int p = k & 1;
        if ((t & 63) == 0) { rv[p][wv] = bv; ri[p][wv] = bi; }
        __syncthreads();
        float v = rv[p][0]; int ix = ri[p][0];
#pragma unroll
        for (int j2 = 1; j2 < 8; j2++) {
            float v2 = rv[p][j2]; int i2 = ri[p][j2];
            if (v2 > v || (v2 == v && i2 < ix)) { v = v2; ix = i2; }
        }
        cur = ix;
    }
}

// ---------------- Ball query ---------------- (unchanged, fast)
__global__ __launch_bounds__(256) void ballq_kernel(const float* __restrict__ xyz,
                                                    const int* __restrict__ fps_idx,
                                                    int* __restrict__ ball_idx) {
#pragma clang fp contract(off)
    __shared__ float cd[CAP];
    __shared__ int   ci[CAP];
    __shared__ int   cnt;
    __shared__ float rv[4];
    __shared__ int   ri[4];
    __shared__ int   slots[33];
    int blk = blockIdx.x;
    int b = blk >> 10, m = blk & (M_ - 1);
    int t = threadIdx.x;
    if (t == 0) cnt = 0;
    __syncthreads();
    const float* xb = xyz + (size_t)b * N_ * 3;
    int cidx = fps_idx[b*M_ + m];
    float cx = xb[cidx*3+0], cy = xb[cidx*3+1], cz = xb[cidx*3+2];
    float bv = 3.4e38f; int bi = 0x7fffffff;
    for (int i = t; i < N_; i += 256) {
        float dx = xb[i*3+0] - cx, dy = xb[i*3+1] - cy, dz = xb[i*3+2] - cz;
        float t0 = dx*dx, t1 = dy*dy, t2 = dz*dz;
        float d = (t0 + t1) + t2;
        if (d < bv || (d == bv && i < bi)) { bv = d; bi = i; }
        if (d <= R2) {
            int p = atomicAdd(&cnt, 1);
            if (p < CAP) { cd[p] = d; ci[p] = i; }
        }
    }
    for (int off = 32; off >= 1; off >>= 1) {
        float ov = __shfl_xor(bv, off, 64);
        int   oi = __shfl_xor(bi, off, 64);
        if (ov < bv || (ov == bv && oi < bi)) { bv = ov; bi = oi; }
    }
    int w = t >> 6;
    if ((t & 63) == 0) { rv[w] = bv; ri[w] = bi; }
    __syncthreads();
    int n = cnt < CAP ? cnt : CAP;
    for (int j = t; j < n; j += 256) {
        float dj = cd[j]; int ij = ci[j];
        int rank = 0;
        for (int k = 0; k < n; k++) {
            float dk = cd[k]; int ik = ci[k];
            rank += (dk < dj) || (dk == dj && ik < ij);
        }
        if (rank < S_) slots[rank] = ij;
    }
    if (t == 0) {
        float v = rv[0]; int ix = ri[0];
        for (int j = 1; j < 4; j++)
            if (rv[j] < v || (rv[j] == v && ri[j] < ix)) { v = rv[j]; ix = ri[j]; }
        slots[32] = ix;
    }
    __syncthreads();
    if (t < S_) {
        int nearest = (n > 0) ? slots[0] : slots[32];
        int ix = (t < n) ? slots[t] : nearest;
        ball_idx[(size_t)(b*M_ + m)*S_ + t] = ix;
    }
}

// ================= MLP building blocks =================
// Thread map: s = t>>3 (32 rows), g = t&7 (8 column groups). x-row in regs.
// wT (LDS) pitch: D=64 -> natural [k][d]; D=128 -> column-permuted so the 4
// b128 reads per k are conflict-free (8 distinct consecutive 16B addresses).

__device__ inline void stage_w64(const float* __restrict__ w, float* wT, int K, int t) {
    for (int i = t; i < 64*K; i += 256) {
        int d = i / K, k = i - d*K;
        wT[k*64 + d] = w[i];
    }
}
__device__ inline void stage_w128(const float* __restrict__ w, float* wT, int t) {
    for (int i = t; i < 128*64; i += 256) {
        int d = i >> 6, k = i & 63;
        int sidx = ((d>>2)&3)*32 + (d>>4)*4 + (d&3);   // d = g*16 + r*4 + c
        wT[k*128 + sidx] = w[i];
    }
}

template<int K>  // acc[j] <-> d = g*8+j, xs = row base (pitch 68)
__device__ inline void gemm64(const float* xs, const float* wT,
                              const float* __restrict__ bias, int g, float* acc) {
    constexpr int NLD = (K + 3) / 4;
    float xr[NLD*4];
#pragma unroll
    for (int i = 0; i < NLD; i++) *(float4*)&xr[i*4] = *(const float4*)&xs[i*4];
    float4 ba = *(const float4*)&bias[g*8], bb = *(const float4*)&bias[g*8+4];
    acc[0]=ba.x; acc[1]=ba.y; acc[2]=ba.z; acc[3]=ba.w;
    acc[4]=bb.x; acc[5]=bb.y; acc[6]=bb.z; acc[7]=bb.w;
#pragma unroll 8
    for (int k = 0; k < K; k++) {
        float4 wa = *(const float4*)&wT[k*64 + g*8];
        float4 wb = *(const float4*)&wT[k*64 + g*8 + 4];
        float x = xr[k];
        acc[0] += x*wa.x; acc[1] += x*wa.y; acc[2] += x*wa.z; acc[3] += x*wa.w;
        acc[4] += x*wb.x; acc[5] += x*wb.y; acc[6] += x*wb.z; acc[7] += x*wb.w;
    }
}

// acc[j] <-> d = g*16+j
__device__ inline void gemm128(const float* xs, const float* wT,
                               const float* __restrict__ bias, int g, float* acc) {
    float xr[64];
#pragma unroll
    for (int i = 0; i < 16; i++) *(float4*)&xr[i*4] = *(const float4*)&xs[i*4];
#pragma unroll
    for (int r = 0; r < 4; r++) {
        float4 bq = *(const float4*)&bias[g*16 + r*4];
        acc[r*4+0]=bq.x; acc[r*4+1]=bq.y; acc[r*4+2]=bq.z; acc[r*4+3]=bq.w;
    }
#pragma unroll 4
    for (int k = 0; k < 64; k++) {
        float x = xr[k];
#pragma unroll
        for (int r = 0; r < 4; r++) {
            float4 w = *(const float4*)&wT[k*128 + r*32 + g*4];
            acc[r*4+0] += x*w.x; acc[r*4+1] += x*w.y; acc[r*4+2] += x*w.z; acc[r*4+3] += x*w.w;
        }
    }
}

// shfl-reduce over s-in-wave (lane bits 3..5), LDS combine, global slice add.
template<int ND>
__device__ inline void stats_reduce(float* acc, int t, float* red, float* part) {
    constexpr int D = ND*8;
    int g = t & 7;
    float sq[ND];
#pragma unroll
    for (int j = 0; j < ND; j++) sq[j] = acc[j]*acc[j];
#pragma unroll
    for (int m = 8; m <= 32; m <<= 1) {
#pragma unroll
        for (int j = 0; j < ND; j++) {
            acc[j] += __shfl_xor(acc[j], m, 64);
            sq[j]  += __shfl_xor(sq[j], m, 64);
        }
    }
    if (((t >> 3) & 7) == 0) {
#pragma unroll
        for (int j = 0; j < ND; j++) {
            atomicAdd(&red[g*ND + j], acc[j]);
            atomicAdd(&red[D + g*ND + j], sq[j]);
        }
    }
    __syncthreads();
    for (int i = t; i < 2*D; i += 256) atomicAdd(&part[i], red[i]);
}

__device__ inline void bnrelu64(const float* acc, const float* __restrict__ ca,
                                const float* __restrict__ cc, int g, float* yrow) {
    float v[8];
#pragma unroll
    for (int j = 0; j < 8; j++) {
        int d = g*8 + j;
        float x = acc[j]*ca[d] + cc[d];
        v[j] = x > 0.f ? x : 0.f;
    }
    *(float4*)&yrow[g*8]   = make_float4(v[0],v[1],v[2],v[3]);
    *(float4*)&yrow[g*8+4] = make_float4(v[4],v[5],v[6],v[7]);
}

__device__ inline void gather_x(const float* __restrict__ xyz, const float* __restrict__ feat,
                                int b, float cx, float cy, float cz,
                                const int* idxs, float* xs, int t) {
    const float* xb = xyz + (size_t)b * N_ * 3;
    for (int i = t; i < S_*C0IN; i += 256) {
        int s = i / C0IN, c = i - s*C0IN;
        int p = idxs[s];
        float v;
        if (c == 0)      v = xb[p*3+0] - cx;
        else if (c == 1) v = xb[p*3+1] - cy;
        else if (c == 2) v = xb[p*3+2] - cz;
        else             v = feat[((size_t)b*N_ + p)*IN_ + (c - 3)];
        xs[s*68 + c] = v;
    }
}

// ---------------- Fallback (recompute) path ----------------
template<int MODE>
__global__ __launch_bounds__(256, 2) void mlp_kernel(
    const float* __restrict__ xyz, const float* __restrict__ feat,
    const int* __restrict__ fps_idx, const int* __restrict__ ball_idx,
    const float* __restrict__ w0, const float* __restrict__ b0,
    const float* __restrict__ w1, const float* __restrict__ b1,
    const float* __restrict__ w2, const float* __restrict__ b2,
    const float* __restrict__ coef, float* __restrict__ stats_part,
    float* __restrict__ out_feat) {
    __shared__ float xs[2176];
    __shared__ float y0s[(MODE >= 1) ? 2176 : 4];
    __shared__ float y1s[(MODE >= 2) ? 2176 : 4];
    __shared__ float wT[(MODE >= 2) ? 8192 : 4352];
    __shared__ float red[(MODE >= 2) ? 256 : 128];
    __shared__ int idxs[32];
    constexpr int REDN = (MODE >= 2) ? 256 : 128;
    int t = threadIdx.x, blk = blockIdx.x;
    int b = blk >> 10;
    int s = t >> 3, g = t & 7;
    int slice = blk & 63;
    if (t < REDN) red[t] = 0.f;
    if (t < 32) idxs[t] = ball_idx[(size_t)blk*32 + t];
    __syncthreads();
    const float* xb = xyz + (size_t)b * N_ * 3;
    int cidx = fps_idx[blk];
    float cx = xb[cidx*3+0], cy = xb[cidx*3+1], cz = xb[cidx*3+2];
    gather_x(xyz, feat, b, cx, cy, cz, idxs, xs, t);
    stage_w64(w0, wT, 67, t);
    __syncthreads();
    float acc[8];
    gemm64<67>(xs + s*68, wT, b0, g, acc);
    if (MODE == 0) { stats_reduce<8>(acc, t, red, stats_part + slice*512); return; }
    bnrelu64(acc, coef, coef + 64, g, y0s + s*68);
    __syncthreads();
    stage_w64(w1, wT, 64, t);
    __syncthreads();
    gemm64<64>(y0s + s*68, wT, b1, g, acc);
    if (MODE == 1) { stats_reduce<8>(acc, t, red, stats_part + slice*512 + 128); return; }
    bnrelu64(acc, coef + 128, coef + 192, g, y1s + s*68);
    __syncthreads();
    stage_w128(w2, wT, t);
    __syncthreads();
    float acc2[16];
    gemm128(y1s + s*68, wT, b2, g, acc2);
    if (MODE == 2) { stats_reduce<16>(acc2, t, red, stats_part + slice*512 + 256); return; }
    // final: bn+relu+max
    const float* ca = coef + 256; const float* cc = coef + 384;
    int* redI = (int*)red;
#pragma unroll
    for (int j = 0; j < 16; j++) {
        int d = g*16 + j;
        float x = acc2[j]*ca[d] + cc[d];
        x = x > 0.f ? x : 0.f;
#pragma unroll
        for (int m = 8; m <= 32; m <<= 1) {
            float o = __shfl_xor(x, m, 64);
            x = o > x ? o : x;
        }
        acc2[j] = x;
    }
    if (((t >> 3) & 7) == 0) {
#pragma unroll
        for (int j = 0; j < 16; j++) atomicMax(&redI[g*16+j], __float_as_int(acc2[j]));
    }
    __syncthreads();
    if (t < 128) out_feat[(size_t)blk*128 + t] = __int_as_float(redI[t]);
}

// ---------------- Fast (z-cached) path ----------------
__global__ __launch_bounds__(256, 3) void f0_kernel(
    const float* __restrict__ xyz, const float* __restrict__ feat,
    const int* __restrict__ fps_idx, const int* __restrict__ ball_idx,
    const float* __restrict__ w0, const float* __restrict__ b0,
    float* __restrict__ z0, float* __restrict__ stats_part) {
    __shared__ float xs[2176];
    __shared__ float wT[4352];
    __shared__ float red[128];
    __shared__ int idxs[32];
    int t = threadIdx.x, blk = blockIdx.x;
    int b = blk >> 10;
    int s = t >> 3, g = t & 7;
    int slice = blk & 63;
    if (t < 128) red[t] = 0.f;
    if (t < 32) idxs[t] = ball_idx[(size_t)blk*32 + t];
    __syncthreads();
    const float* xb = xyz + (size_t)b * N_ * 3;
    int cidx = fps_idx[blk];
    float cx = xb[cidx*3+0], cy = xb[cidx*3+1], cz = xb[cidx*3+2];
    gather_x(xyz, feat, b, cx, cy, cz, idxs, xs, t);
    stage_w64(w0, wT, 67, t);
    __syncthreads();
    float acc[8];
    gemm64<67>(xs + s*68, wT, b0, g, acc);
    float* zr = z0 + ((size_t)blk*32 + s)*64 + g*8;
    *(float4*)zr     = make_float4(acc[0],acc[1],acc[2],acc[3]);
    *(float4*)(zr+4) = make_float4(acc[4],acc[5],acc[6],acc[7]);
    stats_reduce<8>(acc, t, red, stats_part + slice*512);
}

__global__ __launch_bounds__(256, 3) void f1_kernel(
    const float* __restrict__ z0, const float* __restrict__ coef,
    const float* __restrict__ w1, const float* __restrict__ b1,
    float* __restrict__ z1, float* __restrict__ stats_part) {
    __shared__ float xs[2176];
    __shared__ float wT[4096];
    __shared__ float red[128];
    int t = threadIdx.x, blk = blockIdx.x;
    int s = t >> 3, g = t & 7;
    int slice = blk & 63;
    if (t < 128) red[t] = 0.f;
    const float* zr = z0 + (size_t)blk*2048 + t*8;
    int ds = g*8;
    float4 v0 = *(const float4*)zr, v1 = *(const float4*)(zr+4);
    float4 a0 = *(const float4*)&coef[ds],    a1 = *(const float4*)&coef[ds+4];
    float4 c0 = *(const float4*)&coef[64+ds], c1 = *(const float4*)&coef[64+ds+4];
    float4 o0, o1;
    o0.x = fmaxf(v0.x*a0.x + c0.x, 0.f); o0.y = fmaxf(v0.y*a0.y + c0.y, 0.f);
    o0.z = fmaxf(v0.z*a0.z + c0.z, 0.f); o0.w = fmaxf(v0.w*a0.w + c0.w, 0.f);
    o1.x = fmaxf(v1.x*a1.x + c1.x, 0.f); o1.y = fmaxf(v1.y*a1.y + c1.y, 0.f);
    o1.z = fmaxf(v1.z*a1.z + c1.z, 0.f); o1.w = fmaxf(v1.w*a1.w + c1.w, 0.f);
    *(float4*)&xs[s*68 + ds]     = o0;
    *(float4*)&xs[s*68 + ds + 4] = o1;
    stage_w64(w1, wT, 64, t);
    __syncthreads();
    float acc[8];
    gemm64<64>(xs + s*68, wT, b1, g, acc);
    float* zw = z1 + (size_t)blk*2048 + (size_t)s*64 + g*8;
    *(float4*)zw     = make_float4(acc[0],acc[1],acc[2],acc[3]);
    *(float4*)(zw+4) = make_float4(acc[4],acc[5],acc[6],acc[7]);
    stats_reduce<8>(acc, t, red, stats_part + slice*512 + 128);
}

__global__ __launch_bounds__(256, 3) void f2_kernel(
    const float* __restrict__ z1, const float* __restrict__ coef,  // a1@0, c1@64
    const float* __restrict__ w2, const float* __restrict__ b2,
    float* __restrict__ z2, float* __restrict__ stats_part) {
    __shared__ float xs[2176];
    __shared__ float wT[8192];
    __shared__ float red[256];
    int t = threadIdx.x, blk = blockIdx.x;
    int s = t >> 3, g = t & 7;
    int slice = blk & 63;
    if (t < 256) red[t] = 0.f;
    const float* zr = z1 + (size_t)blk*2048 + t*8;
    int ds = g*8;
    float4 v0 = *(const float4*)zr, v1 = *(const float4*)(zr+4);
    float4 a0 = *(const float4*)&coef[ds],    a1 = *(const float4*)&coef[ds+4];
    float4 c0 = *(const float4*)&coef[64+ds], c1 = *(const float4*)&coef[64+ds+4];
    float4 o0, o1;
    o0.x = fmaxf(v0.x*a0.x + c0.x, 0.f); o0.y = fmaxf(v0.y*a0.y + c0.y, 0.f);
    o0.z = fmaxf(v0.z*a0.z + c0.z, 0.f); o0.w = fmaxf(v0.w*a0.w + c0.w, 0.f);
    o1.x = fmaxf(v1.x*a1.x + c1.x, 0.f); o1.y = fmaxf(v1.y*a1.y + c1.y, 0.f);
    o1.z = fmaxf(v1.z*a1.z + c1.z, 0.f); o1.w = fmaxf(v1.w*a1.w + c1.w, 0.f);
    *(float4*)&xs[s*68 + ds]     = o0;
    *(float4*)&xs[s*68 + ds + 4] = o1;
    stage_w128(w2, wT, t);
    __syncthreads();
    float acc[16];
    gemm128(xs + s*68, wT, b2, g, acc);
    float* zw = z2 + ((size_t)blk*32 + s)*128 + g*16;
#pragma unroll
    for (int r = 0; r < 4; r++)
        *(float4*)(zw + r*4) = make_float4(acc[r*4],acc[r*4+1],acc[r*4+2],acc[r*4+3]);
    stats_reduce<16>(acc, t, red, stats_part + slice*512 + 256);
}

__global__ __launch_bounds__(256) void f3_kernel(
    const float* __restrict__ z2, const float* __restrict__ coef,  // a2@0, c2@128
    float* __restrict__ out_feat) {
    __shared__ int red[128];
    int t = threadIdx.x, blk = blockIdx.x;
    int g = t & 7;
    if (t < 128) red[t] = 0;
    __syncthreads();
    const float* zr = z2 + (size_t)blk*4096 + t*16;
#pragma unroll
    for (int r = 0; r < 4; r++) {
        float4 v = *(const float4*)(zr + r*4);
        float4 a = *(const float4*)&coef[g*16 + r*4];
        float4 c = *(const float4*)&coef[128 + g*16 + r*4];
        float x0 = fmaxf(v.x*a.x + c.x, 0.f);
        float x1 = fmaxf(v.y*a.y + c.y, 0.f);
        float x2 = fmaxf(v.z*a.z + c.z, 0.f);
        float x3 = fmaxf(v.w*a.w + c.w, 0.f);
#pragma unroll
        for (int m = 8; m <= 32; m <<= 1) {
            x0 = fmaxf(x0, __shfl_xor(x0, m, 64));
            x1 = fmaxf(x1, __shfl_xor(x1, m, 64));
            x2 = fmaxf(x2, __shfl_xor(x2, m, 64));
            x3 = fmaxf(x3, __shfl_xor(x3, m, 64));
        }
        if (((t >> 3) & 7) == 0) {
            atomicMax(&red[g*16 + r*4 + 0], __float_as_int(x0));
            atomicMax(&red[g*16 + r*4 + 1], __float_as_int(x1));
            atomicMax(&red[g*16 + r*4 + 2], __float_as_int(x2));
            atomicMax(&red[g*16 + r*4 + 3], __float_as_int(x3));
        }
    }
    __syncthreads();
    if (t < 128) out_feat[(size_t)blk*128 + t] = __int_as_float(red[t]);
}

// sum 64 slices -> mean/var -> affine coefs
__global__ void finalize_kernel(const float* __restrict__ part,
                                const float* __restrict__ gamma,
                                const float* __restrict__ beta,
                                float* __restrict__ coef, int C) {
    int t = threadIdx.x;
    if (t < C) {
        float sum = 0.f, sq = 0.f;
        for (int sl = 0; sl < 64; sl++) {
            sum += part[sl*512 + t];
            sq  += part[sl*512 + C + t];
        }
        float inv_n = 1.0f / (float)NTOT;
        float mean = sum * inv_n;
        float var = sq * inv_n - mean * mean;
        float rstd = 1.0f / sqrtf(var + 1e-5f);
        float a = gamma[t] * rstd;
        coef[t] = a;
        coef[C + t] = beta[t] - mean * a;
    }
}

extern "C" void kernel_launch(void* const* d_in, const int* in_sizes, int n_in,
                              void* d_out, int out_size, void* d_ws, size_t ws_size,
                              hipStream_t stream) {
    const float* xyz  = (const float*)d_in[0];
    const float* feat = (const float*)d_in[1];
    const float* w0 = (const float*)d_in[2];  const float* b0 = (const float*)d_in[3];
    const float* g0 = (const float*)d_in[4];  const float* be0 = (const float*)d_in[5];
    const float* w1 = (const float*)d_in[6];  const float* b1 = (const float*)d_in[7];
    const float* g1 = (const float*)d_in[8];  const float* be1 = (const float*)d_in[9];
    const float* w2 = (const float*)d_in[10]; const float* b2 = (const float*)d_in[11];
    const float* g2 = (const float*)d_in[12]; const float* be2 = (const float*)d_in[13];
    float* out_xyz  = (float*)d_out;
    float* out_feat = out_xyz + B_*M_*3;

    char* ws = (char*)d_ws;
    int* fps_i  = (int*)ws;                                  // 65536 B
    int* ball_i = (int*)(ws + 65536);                        // 2097152 B
    float* stats_part = (float*)(ws + 65536 + 2097152);      // 64*512*4 = 131072 B
    float* coef = (float*)(ws + 65536 + 2097152 + 131072);   // 2048 B
    size_t zA_off = (size_t)4 << 20;
    size_t zB_off = zA_off + 268435456ull;                   // zA: 256 MB (z0 then z2)
    bool fast = ws_size >= zB_off + 134217728ull;            // zB: 128 MB (z1)
    float* zA = (float*)(ws + zA_off);
    float* zB = (float*)(ws + zB_off);

    hipMemsetAsync(stats_part, 0, 131072, stream);
    fps_kernel<<<B_, 512, 0, stream>>>(xyz, fps_i, out_xyz);
    ballq_kernel<<<B_*M_, 256, 0, stream>>>(xyz, fps_i, ball_i);
    if (fast) {
        f0_kernel<<<B_*M_, 256, 0, stream>>>(xyz, feat, fps_i, ball_i, w0, b0, zA, stats_part);
        finalize_kernel<<<1, 64, 0, stream>>>(stats_part, g0, be0, coef, 64);
        f1_kernel<<<B_*M_, 256, 0, stream>>>(zA, coef, w1, b1, zB, stats_part);
        finalize_kernel<<<1, 64, 0, stream>>>(stats_part + 128, g1, be1, coef + 128, 64);
        f2_kernel<<<B_*M_, 256, 0, stream>>>(zB, coef + 128, w2, b2, zA, stats_part);
        finalize_kernel<<<1, 128, 0, stream>>>(stats_part + 256, g2, be2, coef + 256, 128);
        f3_kernel<<<B_*M_, 256, 0, stream>>>(zA, coef + 256, out_feat);
    } else {
        mlp_kernel<0><<<B_*M_, 256, 0, stream>>>(xyz, feat, fps_i, ball_i,
            w0, b0, w1, b1, w2, b2, coef, stats_part, out_feat);
        finalize_kernel<<<1, 64, 0, stream>>>(stats_part, g0, be0, coef, 64);
        mlp_kernel<1><<<B_*M_, 256, 0, stream>>>(xyz, feat, fps_i, ball_i,
            w0, b0, w1, b1, w2, b2, coef, stats_part, out_feat);
        finalize_kernel<<<1, 64, 0, stream>>>(stats_part + 128, g1, be1, coef + 128, 64);
        mlp_kernel<2><<<B_*M_, 256, 0, stream>>>(xyz, feat, fps_i, ball_i,
            w0, b0, w1, b1, w2, b2, coef, stats_part, out_feat);
        finalize_kernel<<<1, 128, 0, stream>>>(stats_part + 256, g2, be2, coef + 256, 128);
        mlp_kernel<3><<<B_*M_, 256, 0, stream>>>(xyz, feat, fps_i, ball_i,
            w0, b0, w1, b1, w2, b2, coef, stats_part, out_feat);
    }
}